// Round 2
// baseline (174.830 us; speedup 1.0000x reference)
//
#include <hip/hip_runtime.h>
#include <stdint.h>

// MeshConvPoint: B=8, C=64, V=25000, D=12, O=64
// out[b,o,v] = bias[o] + sum_c W0[o,c]*x[b,c,v] + (1/deg)*sum_{d<deg} y1[b,o,nbr[b,v,d]]
//
// R9: split transpose out of the GEMM. R8 counters: ygemm 45.7us, all pipes
// idle (2.5% MFMA / 11% VALU / 23% HBM / 21% occ). Diagnosis: VGPR_Count=72
// is arch-only; acc[2][8] adds 64 AGPRs -> 136 regs/wave -> 3 waves/SIMD
// residency cap, each wave carrying a serial load->pack->LDS->MFMA chain.
// Now: xt_kernel pre-transposes x to bf16 [b][v][c] (128B/vertex row,
// BW-bound, 8 waves/SIMD), and ygemm2 is LDS-free: B-frag = 1 global u32x4
// per (s,kt) from xt, ~110 regs -> 4 waves/SIMD (__launch_bounds__(256,4)),
// chain collapses to load->MFMA. gather_out / wt unchanged (isolation).
// Tiered ws: full (xt+y0+y1) -> R8 path -> fallback. XCD pin: blockIdx&7=b.

#define NB 8
#define NC 64
#define NV 25000
#define ND 12
#define NO 64
#define VTILE 128
#define VROW 32        // xt row stride in dwords (64 bf16 = 128 B)
#define NGT 196        // ceil(25000/128) vertex tiles for gemm
#define XTT 391        // ceil(25000/64)  vertex tiles for transpose
#define GVT 782        // ceil(25000/32)  vertex tiles for gather (32 v / block)

typedef uint32_t u32x4 __attribute__((ext_vector_type(4)));
typedef uint32_t u32x2 __attribute__((ext_vector_type(2)));
typedef __bf16  bf16x8 __attribute__((ext_vector_type(8)));
typedef float   f32x4  __attribute__((ext_vector_type(4)));

__device__ inline uint32_t bf16pack(float a, float b) {
    uint32_t ua = __float_as_uint(a), ub = __float_as_uint(b);
    ua = (ua + 0x7fffu + ((ua >> 16) & 1u)) >> 16;
    ub = (ub + 0x7fffu + ((ub >> 16) & 1u)) >> 16;
    return ua | (ub << 16);
}
__device__ inline float blo(uint32_t u) { return __uint_as_float(u << 16); }
__device__ inline float bhi(uint32_t u) { return __uint_as_float(u & 0xffff0000u); }

// ---- K0: W[o][c][k] -> Wcb[m][c] bf16, m = k*64 + o ----
__global__ __launch_bounds__(256) void wt_kernel(const float* __restrict__ W,
                                                 uint32_t* __restrict__ Wcb) {
    int i = blockIdx.x * 256 + threadIdx.x;  // i in [0, 4096)
    int m = i >> 5;             // 0..127
    int c = (i & 31) * 2;       // 0..62 even
    int k = m >> 6;             // plane
    int o = m & 63;
    float s0 = W[o * (NC * 2) + c * 2 + k];
    float s1 = W[o * (NC * 2) + (c + 1) * 2 + k];
    Wcb[i] = bf16pack(s0, s1);
}

// ---- K0b: transpose x[b][c][v] f32 -> xt[b][v][c] bf16 (row = 128 B) ----
// 64v x 64c tile per block. Read: wave w loads channel slab c = w*16+r,
// 64 consecutive v per instr (256B coalesced). LDS [c][v] pad 65 -> 2-way
// banks on both phases (free). Write: thread covers (v, 16-channel chunk),
// 2 x u32x4 per thread, full 128B line per vertex across 4 threads.
__global__ __launch_bounds__(256) void xt_kernel(const float* __restrict__ x,
                                                 uint32_t* __restrict__ xt) {
    __shared__ float lds[64 * 65];
    const int b = blockIdx.x & 7;      // XCD pin
    const int tile = blockIdx.x >> 3;
    const int vbase = tile * 64;
    const int t = threadIdx.x;
    const int lane = t & 63, wave = t >> 6;
    const float* xb = x + (size_t)b * NC * NV;

    int vg = vbase + lane;
    if (vg >= NV) vg = NV - 1;
#pragma unroll
    for (int r = 0; r < 16; ++r) {
        const int c = wave * 16 + r;
        lds[c * 65 + lane] = __builtin_nontemporal_load(xb + (size_t)c * NV + vg);
    }
    __syncthreads();

    const int vl = t >> 2;           // 0..63
    const int q  = t & 3;            // 16-channel chunk
    const int vo = vbase + vl;
    if (vo < NV) {
        uint32_t w[8];
#pragma unroll
        for (int i = 0; i < 8; ++i) {
            const int c = q * 16 + i * 2;
            w[i] = bf16pack(lds[c * 65 + vl], lds[(c + 1) * 65 + vl]);
        }
        uint32_t* dst = xt + ((size_t)b * NV + vo) * VROW + q * 8;
        *reinterpret_cast<u32x4*>(dst)     = (u32x4){w[0], w[1], w[2], w[3]};
        *reinterpret_cast<u32x4*>(dst + 4) = (u32x4){w[4], w[5], w[6], w[7]};
    }
}

// ---- K1: LDS-free MFMA GEMM reading pre-transposed xt ----
// B-frag: lane (l15,lq) reads 16B at xt[v=..+l15] row + kt*64 + lq*16 bytes
// -> channels kt*32 + lq*8 + 0..7, same fragment layout as Wcb A-frags.
__global__ __launch_bounds__(256, 4) void ygemm2(const uint32_t* __restrict__ xt,
                                                 const uint32_t* __restrict__ Wcb,
                                                 const float* __restrict__ bias,
                                                 uint32_t* __restrict__ y0,
                                                 uint32_t* __restrict__ y1) {
    const int b = blockIdx.x & 7;      // XCD pin
    const int tile = blockIdx.x >> 3;
    const int vbase = tile * VTILE;
    const int lane = threadIdx.x & 63, wave = threadIdx.x >> 6;
    const int l15 = lane & 15, lq = lane >> 4;
    const uint32_t* xtb = xt + (size_t)b * NV * VROW;

    union BF { u32x4 q; bf16x8 v; } bf[2][2];  // [sub][kt]
#pragma unroll
    for (int s = 0; s < 2; ++s) {
        int v = vbase + wave * 32 + s * 16 + l15;
        if (v >= NV) v = NV - 1;
        const uint32_t* xr = xtb + (size_t)v * VROW;
#pragma unroll
        for (int kt = 0; kt < 2; ++kt)
            bf[s][kt].q = *reinterpret_cast<const u32x4*>(xr + kt * 16 + lq * 4);
    }

    f32x4 acc[2][8];
#pragma unroll
    for (int s = 0; s < 2; ++s)
#pragma unroll
        for (int mt = 0; mt < 8; ++mt) acc[s][mt] = (f32x4){0.f, 0.f, 0.f, 0.f};

    // A frags loaded once per (kt,mt), reused for both subtiles (L1-resident)
#pragma unroll
    for (int kt = 0; kt < 2; ++kt) {
#pragma unroll
        for (int mt = 0; mt < 8; ++mt) {
            union { u32x4 q; bf16x8 v; } au;
            au.q = *(const u32x4*)(Wcb + (size_t)(mt * 16 + l15) * 32 + kt * 16 + lq * 4);
#pragma unroll
            for (int s = 0; s < 2; ++s)
                acc[s][mt] = __builtin_amdgcn_mfma_f32_16x16x32_bf16(au.v, bf[s][kt].v,
                                                                     acc[s][mt], 0, 0, 0);
        }
    }

    // D: lane holds D[m = mt*16 + lq*4 + r][n = v], r = 0..3 consecutive o
#pragma unroll
    for (int s = 0; s < 2; ++s) {
        const int v = vbase + wave * 32 + s * 16 + l15;
        if (v < NV) {
            uint32_t* yr0 = y0 + ((size_t)b * NV + v) * 32;
            uint32_t* yr1 = y1 + ((size_t)b * NV + v) * 32;
#pragma unroll
            for (int mt = 0; mt < 8; ++mt) {
                const int mo = mt * 16 + lq * 4;
                f32x4 a = acc[s][mt];
                if (mt < 4) {  // plane 0: + bias, nt store (read exactly once later)
                    const float* bp = bias + mo;
                    a[0] += bp[0]; a[1] += bp[1]; a[2] += bp[2]; a[3] += bp[3];
                    u32x2 p = {bf16pack(a[0], a[1]), bf16pack(a[2], a[3])};
                    __builtin_nontemporal_store(p, (u32x2*)(yr0 + (mo >> 1)));
                } else {       // plane 1: hot gather target, keep cached in L2
                    u32x2 p = {bf16pack(a[0], a[1]), bf16pack(a[2], a[3])};
                    *(u32x2*)(yr1 + ((mo - 64) >> 1)) = p;
                }
            }
        }
    }
}

// ---- R8 GEMM kept as mid-tier (workspace too small for xt plane) ----
__global__ __launch_bounds__(256) void ygemm_mfma(const float* __restrict__ x,
                                                  const uint32_t* __restrict__ Wcb,
                                                  const float* __restrict__ bias,
                                                  uint32_t* __restrict__ y0,
                                                  uint32_t* __restrict__ y1) {
    __shared__ uint32_t xt[VTILE * 36];

    const int b = blockIdx.x & 7;
    const int tile = blockIdx.x >> 3;
    const int vbase = tile * VTILE;
    const int tid = threadIdx.x;
    const int lane = tid & 63, wave = tid >> 6;
    const float* xb = x + (size_t)b * NC * NV;

    uint32_t* xw = xt + wave * (32 * 36);
    {
        const int vl = lane & 31;
        const int ph = lane >> 5;
        int vg = vbase + wave * 32 + vl;
        if (vg >= NV) vg = NV - 1;
#pragma unroll
        for (int r = 0; r < 16; ++r) {
            const int p = r * 2 + ph;
            const int c = p * 2;
            float s0 = __builtin_nontemporal_load(xb + (size_t)c * NV + vg);
            float s1 = __builtin_nontemporal_load(xb + (size_t)(c + 1) * NV + vg);
            xw[vl * 36 + p] = bf16pack(s0, s1);
        }
    }

    const int l15 = lane & 15, lq = lane >> 4;
    union BF { u32x4 q; bf16x8 v; } bf[2][2];
#pragma unroll
    for (int s = 0; s < 2; ++s) {
        const int rloc = s * 16 + l15;
#pragma unroll
        for (int kt = 0; kt < 2; ++kt)
            bf[s][kt].q = *reinterpret_cast<const u32x4*>(&xw[rloc * 36 + kt * 16 + lq * 4]);
    }

    f32x4 acc[2][8];
#pragma unroll
    for (int s = 0; s < 2; ++s)
#pragma unroll
        for (int mt = 0; mt < 8; ++mt) acc[s][mt] = (f32x4){0.f, 0.f, 0.f, 0.f};

#pragma unroll
    for (int kt = 0; kt < 2; ++kt) {
#pragma unroll
        for (int mt = 0; mt < 8; ++mt) {
            union { u32x4 q; bf16x8 v; } au;
            au.q = *(const u32x4*)(Wcb + (size_t)(mt * 16 + l15) * 32 + kt * 16 + lq * 4);
#pragma unroll
            for (int s = 0; s < 2; ++s)
                acc[s][mt] = __builtin_amdgcn_mfma_f32_16x16x32_bf16(au.v, bf[s][kt].v,
                                                                     acc[s][mt], 0, 0, 0);
        }
    }

#pragma unroll
    for (int s = 0; s < 2; ++s) {
        const int v = vbase + wave * 32 + s * 16 + l15;
        if (v < NV) {
            uint32_t* yr0 = y0 + ((size_t)b * NV + v) * 32;
            uint32_t* yr1 = y1 + ((size_t)b * NV + v) * 32;
#pragma unroll
            for (int mt = 0; mt < 8; ++mt) {
                const int mo = mt * 16 + lq * 4;
                f32x4 a = acc[s][mt];
                if (mt < 4) {
                    const float* bp = bias + mo;
                    a[0] += bp[0]; a[1] += bp[1]; a[2] += bp[2]; a[3] += bp[3];
                    u32x2 p = {bf16pack(a[0], a[1]), bf16pack(a[2], a[3])};
                    __builtin_nontemporal_store(p, (u32x2*)(yr0 + (mo >> 1)));
                } else {
                    u32x2 p = {bf16pack(a[0], a[1]), bf16pack(a[2], a[3])};
                    *(u32x2*)(yr1 + ((mo - 64) >> 1)) = p;
                }
            }
        }
    }
}

// ---- K2: gather, 8 lanes/vertex + LDS transpose for coalesced stores ----
__global__ __launch_bounds__(256) void gather_out(const int* __restrict__ nbr,
                                                  const int* __restrict__ deg,
                                                  const uint32_t* __restrict__ y0,
                                                  const uint32_t* __restrict__ y1,
                                                  float* __restrict__ out) {
    __shared__ float lds[32 * 68];  // [vloc][o], stride 68 to spread banks

    const int b = blockIdx.x & 7;  // same XCD pin as producer
    const int tile = blockIdx.x >> 3;
    const int lane = threadIdx.x & 63;
    const int wave = threadIdx.x >> 6;
    const int s = lane >> 3;
    const int j = lane & 7;
    const int vloc = wave * 8 + s;       // 0..31
    const int v = tile * 32 + vloc;
    const int vc = v < NV ? v : NV - 1;
    const size_t bv = (size_t)b * NV + vc;

    int idxr[ND];
    {
        const int4* p = reinterpret_cast<const int4*>(nbr + bv * ND);
        int4 a0 = p[0], a1 = p[1], a2 = p[2];
        idxr[0] = a0.x; idxr[1] = a0.y; idxr[2]  = a0.z; idxr[3]  = a0.w;
        idxr[4] = a1.x; idxr[5] = a1.y; idxr[6]  = a1.z; idxr[7]  = a1.w;
        idxr[8] = a2.x; idxr[9] = a2.y; idxr[10] = a2.z; idxr[11] = a2.w;
    }
    const int dg = deg[bv];
    const float inv = 1.0f / (float)dg;
    const uint32_t* y1b = y1 + (size_t)b * NV * 32;

    // self row chunk (read once, nt): per instr 8 rows x 128B fully used
    u32x4 su = __builtin_nontemporal_load(
        reinterpret_cast<const u32x4*>(y0 + bv * 32) + j);

    // phase 1: issue all masked row-chunk loads (up to 12 outstanding)
    u32x4 rows[ND];
#pragma unroll
    for (int d = 0; d < ND; ++d) {
        if (d < dg)
            rows[d] = *(reinterpret_cast<const u32x4*>(y1b + (size_t)idxr[d] * 32) + j);
    }

    // phase 2: accumulate
    float ns[8];
#pragma unroll
    for (int t = 0; t < 8; ++t) ns[t] = 0.0f;
#pragma unroll
    for (int d = 0; d < ND; ++d) {
        if (d < dg) {
            u32x4 u = rows[d];
            ns[0] += blo(u[0]); ns[1] += bhi(u[0]);
            ns[2] += blo(u[1]); ns[3] += bhi(u[1]);
            ns[4] += blo(u[2]); ns[5] += bhi(u[2]);
            ns[6] += blo(u[3]); ns[7] += bhi(u[3]);
        }
    }

    // combine + stage to LDS (16B-aligned float4 writes; 68*4 stride)
    {
        float f[8];
        f[0] = __builtin_fmaf(inv, ns[0], blo(su[0]));
        f[1] = __builtin_fmaf(inv, ns[1], bhi(su[0]));
        f[2] = __builtin_fmaf(inv, ns[2], blo(su[1]));
        f[3] = __builtin_fmaf(inv, ns[3], bhi(su[1]));
        f[4] = __builtin_fmaf(inv, ns[4], blo(su[2]));
        f[5] = __builtin_fmaf(inv, ns[5], bhi(su[2]));
        f[6] = __builtin_fmaf(inv, ns[6], blo(su[3]));
        f[7] = __builtin_fmaf(inv, ns[7], bhi(su[3]));
        f32x4 w0 = {f[0], f[1], f[2], f[3]};
        f32x4 w1 = {f[4], f[5], f[6], f[7]};
        *reinterpret_cast<f32x4*>(&lds[vloc * 68 + j * 8])     = w0;
        *reinterpret_cast<f32x4*>(&lds[vloc * 68 + j * 8 + 4]) = w1;
    }
    __syncthreads();

    // store phase: per wave-instruction 2 o-rows x 32 consecutive v (2x128B)
    {
        const int vl = threadIdx.x & 31;
        const int o8 = threadIdx.x >> 5;   // 0..7
        const int vv = tile * 32 + vl;
        if (vv < NV) {
            float* ob = out + (size_t)b * NO * NV + vv;
#pragma unroll
            for (int oo = 0; oo < 8; ++oo) {
                const int o = oo * 8 + o8;
                __builtin_nontemporal_store(lds[vl * 68 + o], ob + (size_t)o * NV);
            }
        }
    }
}

// ---- Fallback (workspace too small): correct but slow ----
__global__ __launch_bounds__(64) void fallback_kernel(const float* __restrict__ x,
                                                      const int* __restrict__ nbr,
                                                      const int* __restrict__ deg,
                                                      const float* __restrict__ W,
                                                      const float* __restrict__ bias,
                                                      float* __restrict__ out) {
    const int bvi = blockIdx.x;
    const int b = bvi / NV, v = bvi % NV;
    const int o = threadIdx.x;
    const int degv = deg[bvi];
    const float inv = 1.0f / (float)degv;
    float acc = bias[o];
    for (int c = 0; c < NC; ++c) {
        const float* xc = x + ((size_t)b * NC + c) * NV;
        float m = 0.0f;
        for (int d = 0; d < degv; ++d) m += xc[nbr[(size_t)bvi * ND + d]];
        acc += W[o * (NC * 2) + c * 2] * xc[v] + W[o * (NC * 2) + c * 2 + 1] * (m * inv);
    }
    out[((size_t)b * NO + o) * NV + v] = acc;
}

extern "C" void kernel_launch(void* const* d_in, const int* in_sizes, int n_in,
                              void* d_out, int out_size, void* d_ws, size_t ws_size,
                              hipStream_t stream) {
    const float* x    = (const float*)d_in[0];
    const int*   nbr  = (const int*)d_in[1];
    const int*   deg  = (const int*)d_in[2];
    const float* W    = (const float*)d_in[3];
    const float* bias = (const float*)d_in[4];
    float* out = (float*)d_out;

    const size_t wcb_dw = 4096;                   // 128x64 bf16 as dwords
    const size_t yplane = (size_t)NB * NV * 32;   // dwords per plane (= xt size)
    const size_t need_full = (wcb_dw + 3 * yplane) * 4;   // xt + y0 + y1
    const size_t need_mid  = (wcb_dw + 2 * yplane) * 4;   // y0 + y1 only
    if (ws_size >= need_full) {
        uint32_t* Wcb = (uint32_t*)d_ws;
        uint32_t* xtb = Wcb + wcb_dw;
        uint32_t* y0  = xtb + yplane;
        uint32_t* y1  = y0 + yplane;
        wt_kernel<<<dim3(16), 256, 0, stream>>>(W, Wcb);
        xt_kernel<<<dim3(NB * XTT), 256, 0, stream>>>(x, xtb);
        ygemm2<<<dim3(NB * NGT), 256, 0, stream>>>(xtb, Wcb, bias, y0, y1);
        gather_out<<<dim3(NB * GVT), 256, 0, stream>>>(nbr, deg, y0, y1, out);
    } else if (ws_size >= need_mid) {
        uint32_t* Wcb = (uint32_t*)d_ws;
        uint32_t* y0 = Wcb + wcb_dw;
        uint32_t* y1 = y0 + yplane;
        wt_kernel<<<dim3(16), 256, 0, stream>>>(W, Wcb);
        ygemm_mfma<<<dim3(NB * NGT), 256, 0, stream>>>(x, Wcb, bias, y0, y1);
        gather_out<<<dim3(NB * GVT), 256, 0, stream>>>(nbr, deg, y0, y1, out);
    } else {
        fallback_kernel<<<dim3(NB * NV), 64, 0, stream>>>(x, nbr, deg, W, bias, out);
    }
}

// Round 3
// 168.842 us; speedup vs baseline: 1.0355x; 1.0355x over previous
//
#include <hip/hip_runtime.h>
#include <stdint.h>

// MeshConvPoint: B=8, C=64, V=25000, D=12, O=64
// out[b,o,v] = bias[o] + sum_c W0[o,c]*x[b,c,v] + (1/deg)*sum_{d<deg} y1[b,o,nbr[b,v,d]]
//
// R10: fuse the pipeline, kill the y0 plane. R9 counters: every kernel now
// under the 42us harness fill, but total flat -- xt_kernel's 12us + launch
// overhead ate ygemm2's gain, and y0 (25.6MB write + 25.6MB read) was a pure
// HBM round-trip for data the gather can compute itself.
//   K1 xty1: x -> LDS bf16 pack -> {coalesced xt rows out, plane-1 GEMM -> y1}.
//            One x read, no xt re-read, acc[4]=16 AGPRs -> high occupancy.
//   K2 gather_out: + plane-0 MFMA from xt/Wcb (self term, f32 all the way,
//            bias here), then neighbor mean adds into the same LDS tile.
// Traffic: 51.2 x + 9.6 nbr + 25.6 xt(L2-warm re-read) in, 51.2 xt+y1 +
// 51.2 out written. XCD pin everywhere: blockIdx.x&7 = b.

#define NB 8
#define NC 64
#define NV 25000
#define ND 12
#define NO 64
#define VROW 32        // xt/y1 row stride in dwords (64 bf16 = 128 B)
#define ATL 391        // ceil(25000/64) tiles for xty1 (64 v / block)
#define GVT 782        // ceil(25000/32) tiles for gather (32 v / block)

typedef uint32_t u32x4 __attribute__((ext_vector_type(4)));
typedef uint32_t u32x2 __attribute__((ext_vector_type(2)));
typedef __bf16  bf16x8 __attribute__((ext_vector_type(8)));
typedef float   f32x4  __attribute__((ext_vector_type(4)));

__device__ inline uint32_t bf16pack(float a, float b) {
    uint32_t ua = __float_as_uint(a), ub = __float_as_uint(b);
    ua = (ua + 0x7fffu + ((ua >> 16) & 1u)) >> 16;
    ub = (ub + 0x7fffu + ((ub >> 16) & 1u)) >> 16;
    return ua | (ub << 16);
}
__device__ inline float blo(uint32_t u) { return __uint_as_float(u << 16); }
__device__ inline float bhi(uint32_t u) { return __uint_as_float(u & 0xffff0000u); }

// ---- K0: W[o][c][k] -> Wcb[m][c-pair] bf16, m = k*64 + o ----
__global__ __launch_bounds__(256) void wt_kernel(const float* __restrict__ W,
                                                 uint32_t* __restrict__ Wcb) {
    int i = blockIdx.x * 256 + threadIdx.x;  // i in [0, 4096)
    int m = i >> 5;             // 0..127
    int c = (i & 31) * 2;       // 0..62 even
    int k = m >> 6;             // plane
    int o = m & 63;
    float s0 = W[o * (NC * 2) + c * 2 + k];
    float s1 = W[o * (NC * 2) + (c + 1) * 2 + k];
    Wcb[i] = bf16pack(s0, s1);
}

// ---- K1: x[b][c][v] -> xt[b][v][c] bf16 rows + plane-1 GEMM -> y1 ----
// 64 v / block, 256 thr. Stage: lane=v, wave covers 16 channels; pack bf16
// pairs straight to LDS rows [v][c-pair] stride 36 dw (144B, 16B-aligned).
// Then: xt store (4 lanes = one contiguous 128B row; wave = 2KB contiguous)
// and plane-1 GEMM (wave w: v-subtile w, 4 mt x 2 kt = 8 MFMAs, 16 AGPRs).
__global__ __launch_bounds__(256) void xty1(const float* __restrict__ x,
                                            const uint32_t* __restrict__ Wcb,
                                            uint32_t* __restrict__ xt,
                                            uint32_t* __restrict__ y1) {
    __shared__ uint32_t lb[64 * 36];
    const int b = blockIdx.x & 7;      // XCD pin
    const int tile = blockIdx.x >> 3;
    const int vbase = tile * 64;
    const int lane = threadIdx.x & 63, wave = threadIdx.x >> 6;
    const float* xb = x + (size_t)b * NC * NV;

    {
        int vg = vbase + lane;
        if (vg >= NV) vg = NV - 1;
#pragma unroll
        for (int rr = 0; rr < 8; ++rr) {
            const int c = wave * 16 + rr * 2;
            float s0 = __builtin_nontemporal_load(xb + (size_t)c * NV + vg);
            float s1 = __builtin_nontemporal_load(xb + (size_t)(c + 1) * NV + vg);
            lb[lane * 36 + wave * 8 + rr] = bf16pack(s0, s1);
        }
    }
    __syncthreads();

    // xt rows out: thread (vl = t>>2, q = t&3) stores 32B of row vl
    {
        const int vl = threadIdx.x >> 2, q = threadIdx.x & 3;
        const int vo = vbase + vl;
        if (vo < NV) {
            u32x4 w0 = *reinterpret_cast<const u32x4*>(&lb[vl * 36 + q * 8]);
            u32x4 w1 = *reinterpret_cast<const u32x4*>(&lb[vl * 36 + q * 8 + 4]);
            uint32_t* dst = xt + ((size_t)b * NV + vo) * VROW + q * 8;
            *reinterpret_cast<u32x4*>(dst)     = w0;
            *reinterpret_cast<u32x4*>(dst + 4) = w1;
        }
    }

    // plane-1 GEMM: wave w covers v = vbase + w*16 + l15
    const int l15 = lane & 15, lq = lane >> 4;
    union BF { u32x4 q; bf16x8 v; } bf[2];
#pragma unroll
    for (int kt = 0; kt < 2; ++kt)
        bf[kt].q = *reinterpret_cast<const u32x4*>(
            &lb[(wave * 16 + l15) * 36 + kt * 16 + lq * 4]);

    f32x4 acc[4];
#pragma unroll
    for (int mt = 0; mt < 4; ++mt) acc[mt] = (f32x4){0.f, 0.f, 0.f, 0.f};

#pragma unroll
    for (int kt = 0; kt < 2; ++kt) {
#pragma unroll
        for (int mt = 0; mt < 4; ++mt) {
            union { u32x4 q; bf16x8 v; } au;
            au.q = *(const u32x4*)(Wcb + (size_t)(64 + mt * 16 + l15) * 32 + kt * 16 + lq * 4);
            acc[mt] = __builtin_amdgcn_mfma_f32_16x16x32_bf16(au.v, bf[kt].v, acc[mt], 0, 0, 0);
        }
    }

    // y1 row store: lane holds D[o = mt*16 + lq*4 + r][v = l15]
    const int v = vbase + wave * 16 + l15;
    if (v < NV) {
        uint32_t* yr = y1 + ((size_t)b * NV + v) * VROW;
#pragma unroll
        for (int mt = 0; mt < 4; ++mt) {
            f32x4 a = acc[mt];
            u32x2 p = {bf16pack(a[0], a[1]), bf16pack(a[2], a[3])};
            *(u32x2*)(yr + mt * 8 + lq * 2) = p;
        }
    }
}

// ---- K2: gather + plane-0 self term (fused), 32 v / block ----
// Wave w computes self[o in w*16..w*16+16) for all 32 v by MFMA (xt B-frags,
// Wcb plane-0 A-frags), writes self+bias (f32) into lds[v][o]; barrier;
// neighbor mean (8 lanes/vertex) adds in; barrier; coalesced store.
__global__ __launch_bounds__(256) void gather_out(const int* __restrict__ nbr,
                                                  const int* __restrict__ deg,
                                                  const uint32_t* __restrict__ xt,
                                                  const uint32_t* __restrict__ Wcb,
                                                  const float* __restrict__ bias,
                                                  const uint32_t* __restrict__ y1,
                                                  float* __restrict__ out) {
    __shared__ float lds[32 * 68];  // [vloc][o], stride 68 to spread banks

    const int b = blockIdx.x & 7;  // same XCD pin as producer
    const int tile = blockIdx.x >> 3;
    const int lane = threadIdx.x & 63;
    const int wave = threadIdx.x >> 6;
    const int s8 = lane >> 3;
    const int j = lane & 7;
    const int vloc = wave * 8 + s8;      // 0..31
    const int v = tile * 32 + vloc;
    const int vc = v < NV ? v : NV - 1;
    const size_t bv = (size_t)b * NV + vc;

    // neighbor indices (issue early; long-latency)
    int idxr[ND];
    {
        const int4* p = reinterpret_cast<const int4*>(nbr + bv * ND);
        int4 a0 = p[0], a1 = p[1], a2 = p[2];
        idxr[0] = a0.x; idxr[1] = a0.y; idxr[2]  = a0.z; idxr[3]  = a0.w;
        idxr[4] = a1.x; idxr[5] = a1.y; idxr[6]  = a1.z; idxr[7]  = a1.w;
        idxr[8] = a2.x; idxr[9] = a2.y; idxr[10] = a2.z; idxr[11] = a2.w;
    }
    const int dg = deg[bv];
    const float inv = 1.0f / (float)dg;
    const uint32_t* y1b = y1 + (size_t)b * NV * VROW;

    // ---- plane-0 self term via MFMA (covers idx-load latency) ----
    const int l15 = lane & 15, lq = lane >> 4;
    {
        const uint32_t* xtb = xt + (size_t)b * NV * VROW;
        union BF { u32x4 q; bf16x8 v; } bfr[2][2];
#pragma unroll
        for (int s = 0; s < 2; ++s) {
            int vv = tile * 32 + s * 16 + l15;
            if (vv >= NV) vv = NV - 1;
            const uint32_t* xr = xtb + (size_t)vv * VROW;
#pragma unroll
            for (int kt = 0; kt < 2; ++kt)
                bfr[s][kt].q = *reinterpret_cast<const u32x4*>(xr + kt * 16 + lq * 4);
        }
        f32x4 acc[2];
        acc[0] = (f32x4){0.f, 0.f, 0.f, 0.f};
        acc[1] = (f32x4){0.f, 0.f, 0.f, 0.f};
#pragma unroll
        for (int kt = 0; kt < 2; ++kt) {
            union { u32x4 q; bf16x8 v; } au;  // plane-0 rows m = wave*16 + l15
            au.q = *(const u32x4*)(Wcb + (size_t)(wave * 16 + l15) * 32 + kt * 16 + lq * 4);
#pragma unroll
            for (int s = 0; s < 2; ++s)
                acc[s] = __builtin_amdgcn_mfma_f32_16x16x32_bf16(au.v, bfr[s][kt].v,
                                                                 acc[s], 0, 0, 0);
        }
        const f32x4 bq = *reinterpret_cast<const f32x4*>(bias + wave * 16 + lq * 4);
#pragma unroll
        for (int s = 0; s < 2; ++s) {
            const int vr = s * 16 + l15;
            const int ob = wave * 16 + lq * 4;
            lds[vr * 68 + ob + 0] = acc[s][0] + bq[0];
            lds[vr * 68 + ob + 1] = acc[s][1] + bq[1];
            lds[vr * 68 + ob + 2] = acc[s][2] + bq[2];
            lds[vr * 68 + ob + 3] = acc[s][3] + bq[3];
        }
    }

    // ---- neighbor rows: issue all masked loads (up to 12 outstanding) ----
    u32x4 rows[ND];
#pragma unroll
    for (int d = 0; d < ND; ++d) {
        if (d < dg)
            rows[d] = *(reinterpret_cast<const u32x4*>(y1b + (size_t)idxr[d] * VROW) + j);
    }

    __syncthreads();  // self terms visible in lds

    // accumulate neighbor mean
    float ns[8];
#pragma unroll
    for (int t = 0; t < 8; ++t) ns[t] = 0.0f;
#pragma unroll
    for (int d = 0; d < ND; ++d) {
        if (d < dg) {
            u32x4 u = rows[d];
            ns[0] += blo(u[0]); ns[1] += bhi(u[0]);
            ns[2] += blo(u[1]); ns[3] += bhi(u[1]);
            ns[4] += blo(u[2]); ns[5] += bhi(u[2]);
            ns[6] += blo(u[3]); ns[7] += bhi(u[3]);
        }
    }

    // combine: f = self + inv * ns, write back (same cells, no race)
    {
        f32x4 c0 = *reinterpret_cast<const f32x4*>(&lds[vloc * 68 + j * 8]);
        f32x4 c1 = *reinterpret_cast<const f32x4*>(&lds[vloc * 68 + j * 8 + 4]);
        c0[0] = __builtin_fmaf(inv, ns[0], c0[0]);
        c0[1] = __builtin_fmaf(inv, ns[1], c0[1]);
        c0[2] = __builtin_fmaf(inv, ns[2], c0[2]);
        c0[3] = __builtin_fmaf(inv, ns[3], c0[3]);
        c1[0] = __builtin_fmaf(inv, ns[4], c1[0]);
        c1[1] = __builtin_fmaf(inv, ns[5], c1[1]);
        c1[2] = __builtin_fmaf(inv, ns[6], c1[2]);
        c1[3] = __builtin_fmaf(inv, ns[7], c1[3]);
        *reinterpret_cast<f32x4*>(&lds[vloc * 68 + j * 8])     = c0;
        *reinterpret_cast<f32x4*>(&lds[vloc * 68 + j * 8 + 4]) = c1;
    }
    __syncthreads();

    // store phase: per wave-instruction 2 o-rows x 32 consecutive v (2x128B)
    {
        const int vl = threadIdx.x & 31;
        const int o8 = threadIdx.x >> 5;   // 0..7
        const int vv = tile * 32 + vl;
        if (vv < NV) {
            float* ob = out + (size_t)b * NO * NV + vv;
#pragma unroll
            for (int oo = 0; oo < 8; ++oo) {
                const int o = oo * 8 + o8;
                __builtin_nontemporal_store(lds[vl * 68 + o], ob + (size_t)o * NV);
            }
        }
    }
}

// ---- Fallback (workspace too small): correct but slow ----
__global__ __launch_bounds__(64) void fallback_kernel(const float* __restrict__ x,
                                                      const int* __restrict__ nbr,
                                                      const int* __restrict__ deg,
                                                      const float* __restrict__ W,
                                                      const float* __restrict__ bias,
                                                      float* __restrict__ out) {
    const int bvi = blockIdx.x;
    const int b = bvi / NV, v = bvi % NV;
    const int o = threadIdx.x;
    const int degv = deg[bvi];
    const float inv = 1.0f / (float)degv;
    float acc = bias[o];
    for (int c = 0; c < NC; ++c) {
        const float* xc = x + ((size_t)b * NC + c) * NV;
        float m = 0.0f;
        for (int d = 0; d < degv; ++d) m += xc[nbr[(size_t)bvi * ND + d]];
        acc += W[o * (NC * 2) + c * 2] * xc[v] + W[o * (NC * 2) + c * 2 + 1] * (m * inv);
    }
    out[((size_t)b * NO + o) * NV + v] = acc;
}

extern "C" void kernel_launch(void* const* d_in, const int* in_sizes, int n_in,
                              void* d_out, int out_size, void* d_ws, size_t ws_size,
                              hipStream_t stream) {
    const float* x    = (const float*)d_in[0];
    const int*   nbr  = (const int*)d_in[1];
    const int*   deg  = (const int*)d_in[2];
    const float* W    = (const float*)d_in[3];
    const float* bias = (const float*)d_in[4];
    float* out = (float*)d_out;

    const size_t wcb_dw = 4096;                     // 128x64 bf16 as dwords
    const size_t plane  = (size_t)NB * NV * VROW;   // dwords per bf16 plane
    const size_t need = (wcb_dw + 2 * plane) * 4;   // Wcb + xt + y1
    if (ws_size >= need) {
        uint32_t* Wcb = (uint32_t*)d_ws;
        uint32_t* xtb = Wcb + wcb_dw;
        uint32_t* y1  = xtb + plane;
        wt_kernel<<<dim3(16), 256, 0, stream>>>(W, Wcb);
        xty1<<<dim3(NB * ATL), 256, 0, stream>>>(x, Wcb, xtb, y1);
        gather_out<<<dim3(NB * GVT), 256, 0, stream>>>(nbr, deg, xtb, Wcb, bias, y1, out);
    } else {
        fallback_kernel<<<dim3(NB * NV), 64, 0, stream>>>(x, nbr, deg, W, bias, out);
    }
}